// Round 12
// baseline (134.294 us; speedup 1.0000x reference)
//
#include <hip/hip_runtime.h>
#include <hip/hip_bf16.h>
#include <math.h>

constexpr int D  = 512;
constexpr int H  = 8;
constexpr int DH = 64;
constexpr int B  = 64;
constexpr int NF = 16384;
constexpr int NO = 8192;
constexpr int NT = NF + NO;
constexpr float EPS = 1e-5f;
constexpr float LOG2E = 1.4426950408889634f;

constexpr int PREP_PK   = 512;                  // (b,h) blocks
constexpr int PREP_BND  = PREP_PK;              // 1 block
constexpr int PREP_WG0  = PREP_BND + 1;         // 256 blocks
constexpr int PREP_CVT0 = PREP_WG0 + 256;       // 6144 blocks
constexpr int CVT_BLOCKS = NT * D / 2048;       // 6144
constexpr int PREP_TOTAL = PREP_CVT0 + CVT_BLOCKS;

typedef short short8 __attribute__((ext_vector_type(8)));
typedef float f32x4 __attribute__((ext_vector_type(4)));
typedef unsigned short ushort;
typedef ushort ushort8v __attribute__((ext_vector_type(8)));

__device__ __forceinline__ ushort f2bf(float f) {
  unsigned int x = __float_as_uint(f);
  x += 0x7FFF + ((x >> 16) & 1);   // RNE (inputs finite)
  return (ushort)(x >> 16);
}
__device__ __forceinline__ float bf2f(ushort u) {
  return __uint_as_float(((unsigned int)u) << 16);
}
__device__ __forceinline__ float fast_exp(float x) {   // e^x
  return __builtin_amdgcn_exp2f(x * LOG2E);
}
__device__ __forceinline__ float fast_sigmoid(float z) {
  return __builtin_amdgcn_rcpf(1.0f + __builtin_amdgcn_exp2f(-z * LOG2E));
}
// 8 fp32 -> 8 bf16 (RNE); compiler emits v_cvt_pk_bf16_f32 pairs
__device__ __forceinline__ short8 cvt8(float4 f0, float4 f1) {
  union { short8 v; __hip_bfloat162 h[4]; } u;
  u.h[0] = __float22bfloat162_rn(float2{f0.x, f0.y});
  u.h[1] = __float22bfloat162_rn(float2{f0.z, f0.w});
  u.h[2] = __float22bfloat162_rn(float2{f1.x, f1.y});
  u.h[3] = __float22bfloat162_rn(float2{f1.z, f1.w});
  return u.v;
}
// async global->LDS, 16B per lane; lds dest = wave-uniform base + lane*16
__device__ __forceinline__ void gll16(const void* g, void* l) {
  __builtin_amdgcn_global_load_lds(
      (const __attribute__((address_space(1))) void*)g,
      (__attribute__((address_space(3))) void*)l, 16, 0, 0);
}

// ======== k_prep: [0..511] q-slice+Pk+qbk per (b,h); [512] bounds; ========
// ======== [513..768] Wg^T bf16; [769..6912] node fp32->bf16 cvt     ========
__global__ __launch_bounds__(256) void k_prep(const float* __restrict__ ps,
                                              const float* __restrict__ Wq,
                                              const float* __restrict__ bq,
                                              const float* __restrict__ Wk,
                                              const float* __restrict__ bk,
                                              const float* __restrict__ Wg,
                                              const float* __restrict__ hf,
                                              const float* __restrict__ ho,
                                              const int* __restrict__ fb,
                                              const int* __restrict__ ob,
                                              float* __restrict__ Pk,
                                              float* __restrict__ qbk,
                                              ushort* __restrict__ Wgt,
                                              ushort* __restrict__ nodesb,
                                              int* __restrict__ fstart,
                                              int* __restrict__ ostart) {
  __shared__ float shm[1056];   // pk: [0..511]=ps row, [512..575]=q slice; prepW: 32x33 tile
  const int bid = blockIdx.x, t = threadIdx.x;
  if (bid < PREP_PK) {
    const int b = bid >> 3, h = bid & 7;
    for (int i = t; i < D; i += 256) shm[i] = ps[(size_t)b * D + i];
    __syncthreads();
    // q[col] for col in [h*64, h*64+64): 4 threads per col
    {
      const int j = t >> 2, eq = t & 3;
      const int col = h * 64 + j;
      float acc = 0.f;
      const float* wp = Wq + (size_t)(eq * 128) * D + col;
      #pragma unroll 8
      for (int e = 0; e < 128; ++e) acc += shm[eq * 128 + e] * wp[(size_t)e * D];
      acc += __shfl_xor(acc, 1); acc += __shfl_xor(acc, 2);
      if (eq == 0) shm[512 + j] = acc + bq[col];
    }
    __syncthreads();
    for (int e = t; e < D; e += 256) {
      float acc = 0.f;
      #pragma unroll 8
      for (int j = 0; j < DH; ++j) acc += Wk[(size_t)e * D + h * DH + j] * shm[512 + j];
      Pk[((size_t)b * H + h) * D + e] = acc;
    }
    if (t == 0) {
      float s = 0.f;
      for (int j = 0; j < DH; ++j) s += bk[h * DH + j] * shm[512 + j];
      qbk[b * H + h] = s;
    }
  } else if (bid == PREP_BND) {
    if (t <= B) {
      int lo = 0, hi = NF;
      while (lo < hi) { int mid = (lo + hi) >> 1; if (fb[mid] < t) lo = mid + 1; else hi = mid; }
      fstart[t] = lo;
    } else if (t >= 128 && t <= 128 + B) {
      int v = t - 128;
      int lo = 0, hi = NO;
      while (lo < hi) { int mid = (lo + hi) >> 1; if (ob[mid] < v) lo = mid + 1; else hi = mid; }
      ostart[v] = lo;
    }
  } else if (bid < PREP_CVT0) {
    // Wg transpose 32x32 tiles, 16x16 grid
    float (*tile)[33] = (float(*)[33])shm;
    const int tb = bid - PREP_WG0;
    const int bx = tb & 15, by = tb >> 4;
    const int tx = t & 31, ty = t >> 5;            // ty 0..7
    #pragma unroll
    for (int i = 0; i < 4; ++i)
      tile[ty + i * 8][tx] = Wg[(size_t)(by * 32 + ty + i * 8) * D + bx * 32 + tx];
    __syncthreads();
    #pragma unroll
    for (int i = 0; i < 4; ++i)
      Wgt[(size_t)(bx * 32 + ty + i * 8) * D + by * 32 + tx] = f2bf(tile[tx][ty + i * 8]);
  } else {
    // nodes fp32 -> bf16: 2048 elems per block
    size_t idx = (size_t)(bid - PREP_CVT0) * 2048 + (size_t)t * 8;
    const float* src = (idx < (size_t)NF * D) ? (hf + idx) : (ho + (idx - (size_t)NF * D));
    float4 f0 = *(const float4*)src, f1 = *(const float4*)(src + 4);
    *(short8*)(nodesb + idx) = cvt8(f0, f1);
  }
}

// ------- gate GEMM: gateb = bf16(sigmoid(hf @ Wg + bg)); 128x128, BK=32, all-bf16 LDS ----
__global__ __launch_bounds__(256) void k_gate(const ushort* __restrict__ hfb,
                                              const ushort* __restrict__ Wgt,
                                              const float* __restrict__ bg,
                                              ushort* __restrict__ gateb) {
  __shared__ ushort Asb[2][4096];   // 8KB/buf: [128 rows][32 k] bf16, chunk-swizzled
  __shared__ ushort Bs[2][4096];    // 8KB/buf: [128 cols][32 k] bf16, chunk-swizzled
  const int tid = threadIdx.x, lane = tid & 63, w = tid >> 6;
  const int rowBase = blockIdx.x * 128, colBase = blockIdx.y * 128;
  const int wm = w >> 1, wn = w & 1;
  const int lrow = lane & 15, kg = lane >> 4;

  int ra[2], ca[2], cb[2], cc[2];
  #pragma unroll
  for (int j = 0; j < 2; ++j) {
    int ia = (w * 2 + j) * 64 + lane;          // 0..511
    ra[j] = ia >> 2;                           // row/col 0..127
    ca[j] = (ia & 3) ^ ((ra[j] >> 1) & 3);     // 16B-chunk swizzle
    cb[j] = ra[j];
    cc[j] = ca[j];
  }

#define STAGE(buf, k0)                                                          \
  {                                                                             \
    _Pragma("unroll")                                                           \
    for (int j = 0; j < 2; ++j)                                                 \
      gll16(hfb + (size_t)(rowBase + ra[j]) * D + (k0) + ca[j] * 8,             \
            &Asb[buf][(w * 2 + j) * 512]);                                      \
    _Pragma("unroll")                                                           \
    for (int j = 0; j < 2; ++j)                                                 \
      gll16(Wgt + (size_t)(colBase + cb[j]) * D + (k0) + cc[j] * 8,             \
            &Bs[buf][(w * 2 + j) * 512]);                                       \
  }

  STAGE(0, 0);
  __syncthreads();

  f32x4 acc[4][4] = {};
  for (int t = 0; t < 16; ++t) {
    const int cur = t & 1;
    if (t < 15) STAGE(cur ^ 1, (t + 1) * 32);
    short8 av[4], bv[4];
    #pragma unroll
    for (int m = 0; m < 4; ++m) {
      const int a_r = wm * 64 + m * 16 + lrow;
      av[m] = *(const short8*)&Asb[cur][a_r * 32 + (kg ^ ((a_r >> 1) & 3)) * 8];
    }
    #pragma unroll
    for (int n = 0; n < 4; ++n) {
      const int b_c = wn * 64 + n * 16 + lrow;
      bv[n] = *(const short8*)&Bs[cur][b_c * 32 + (kg ^ ((b_c >> 1) & 3)) * 8];
    }
    #pragma unroll
    for (int m = 0; m < 4; ++m)
      #pragma unroll
      for (int n = 0; n < 4; ++n)
        acc[m][n] = __builtin_amdgcn_mfma_f32_16x16x32_bf16(av[m], bv[n], acc[m][n], 0, 0, 0);
    __syncthreads();
  }
#undef STAGE

  // epilogue: sigmoid + bias -> bf16 global.  C/D map: col=lane&15, row=(lane>>4)*4+reg
  #pragma unroll
  for (int n = 0; n < 4; ++n) {
    const int col = colBase + wn * 64 + n * 16 + lrow;
    const float bgv = bg[col];
    #pragma unroll
    for (int m = 0; m < 4; ++m) {
      const int row0 = rowBase + wm * 64 + m * 16 + kg * 4;
      #pragma unroll
      for (int r = 0; r < 4; ++r)
        gateb[(size_t)(row0 + r) * D + col] = f2bf(fast_sigmoid(acc[m][n][r] + bgv));
    }
  }
}

// ------- scores[n,h] = (nodes[n]·Pk[seg,h] + qbk[seg,h]) / 8 ;  wave per node -------
// Pk block (8 heads x 512 = 16KB) staged in LDS for the block's dominant batch.
__global__ __launch_bounds__(256) void k_scores(const ushort* __restrict__ nodesb,
                                                const int* __restrict__ fb,
                                                const int* __restrict__ ob,
                                                const float* __restrict__ Pk,
                                                const float* __restrict__ qbk,
                                                float* __restrict__ scores) {
  __shared__ float Pks[H * D];   // 16KB
  const int t = threadIdx.x, lane = t & 63;
  const int n0 = blockIdx.x * 4;
  const int b0 = (n0 < NF) ? fb[n0] : ob[n0 - NF];
  {
    const float4* src = (const float4*)(Pk + (size_t)b0 * H * D);
    float4* dst = (float4*)Pks;
    #pragma unroll
    for (int i = 0; i < 4; ++i) dst[t + i * 256] = src[t + i * 256];
  }
  __syncthreads();

  const int n = n0 + (t >> 6);
  const int b = (n < NF) ? fb[n] : ob[n - NF];
  union { short8 v; ushort u[8]; } ux;
  ux.v = *(const short8*)(nodesb + (size_t)n * D + lane * 8);
  float xf[8];
  #pragma unroll
  for (int i = 0; i < 8; ++i) xf[i] = bf2f(ux.u[i]);
  float acc[H];
  if (b == b0) {
    #pragma unroll
    for (int h = 0; h < H; ++h) {
      const float4* p4 = (const float4*)(Pks + h * D + lane * 8);
      float4 p0 = p4[0], p1 = p4[1];
      acc[h] = xf[0] * p0.x + xf[1] * p0.y + xf[2] * p0.z + xf[3] * p0.w +
               xf[4] * p1.x + xf[5] * p1.y + xf[6] * p1.z + xf[7] * p1.w;
    }
  } else {
    #pragma unroll
    for (int h = 0; h < H; ++h) {
      const float4* p4 = (const float4*)(Pk + ((size_t)b * H + h) * D) + lane * 2;
      float4 p0 = p4[0], p1 = p4[1];
      acc[h] = xf[0] * p0.x + xf[1] * p0.y + xf[2] * p0.z + xf[3] * p0.w +
               xf[4] * p1.x + xf[5] * p1.y + xf[6] * p1.z + xf[7] * p1.w;
    }
  }
  #pragma unroll
  for (int h = 0; h < H; ++h) {
    float v = acc[h];
    #pragma unroll
    for (int off = 32; off; off >>= 1) v += __shfl_xor(v, off);
    if (lane == h) scores[(size_t)n * H + h] = (v + qbk[b * H + h]) * 0.125f;
  }
}

// ------- per (b,h): segment max, e = exp(s-m), denom -------
__global__ __launch_bounds__(512) void k_segsoftmax(const float* __restrict__ scores,
                                                    const int* __restrict__ fstart,
                                                    const int* __restrict__ ostart,
                                                    float* __restrict__ evals,
                                                    float* __restrict__ denom) {
  int b = blockIdx.x;
  int h = threadIdx.x >> 6, lane = threadIdx.x & 63;
  int f0 = fstart[b], f1 = fstart[b + 1];
  int o0 = ostart[b], o1 = ostart[b + 1];
  float m = -1e30f;
  for (int i = f0 + lane; i < f1; i += 64) m = fmaxf(m, scores[(size_t)i * H + h]);
  for (int i = o0 + lane; i < o1; i += 64) m = fmaxf(m, scores[(size_t)(NF + i) * H + h]);
  #pragma unroll
  for (int off = 32; off; off >>= 1) m = fmaxf(m, __shfl_xor(m, off));
  float s = 0.f;
  for (int i = f0 + lane; i < f1; i += 64) {
    float e = fast_exp(scores[(size_t)i * H + h] - m);
    evals[(size_t)i * H + h] = e; s += e;
  }
  for (int i = o0 + lane; i < o1; i += 64) {
    float e = fast_exp(scores[(size_t)(NF + i) * H + h] - m);
    evals[(size_t)(NF + i) * H + h] = e; s += e;
  }
  #pragma unroll
  for (int off = 32; off; off >>= 1) s += __shfl_xor(s, off);
  if (lane == 0) denom[b * H + h] = s;
}

// ------- T8[chunk][b][h][e] = sum_{n in chunk of seg b} e[n,h]*nodes[n,e]; 2 cols/thread ----
__global__ __launch_bounds__(256) void k_Taccum(const ushort* __restrict__ nodesb,
                                                const int* __restrict__ fstart,
                                                const int* __restrict__ ostart,
                                                const float* __restrict__ evals,
                                                float* __restrict__ T8) {
  int b = blockIdx.x, chunk = blockIdx.y;
  int e0 = threadIdx.x * 2;
  int f0 = fstart[b], flen = fstart[b + 1] - f0;
  int o0 = ostart[b], olen = ostart[b + 1] - o0;
  int L = flen + olen;
  float acc0[8] = {0.f, 0.f, 0.f, 0.f, 0.f, 0.f, 0.f, 0.f};
  float acc1[8] = {0.f, 0.f, 0.f, 0.f, 0.f, 0.f, 0.f, 0.f};
  for (int idx = chunk; idx < L; idx += 8) {
    int n = (idx < flen) ? (f0 + idx) : (NF + o0 + (idx - flen));
    ushort2 uv = *(const ushort2*)(nodesb + (size_t)n * D + e0);
    float x0 = bf2f(uv.x), x1 = bf2f(uv.y);
    const float4* ev = (const float4*)(evals + (size_t)n * H);
    float4 ea = ev[0], eb = ev[1];
    acc0[0] += ea.x * x0; acc1[0] += ea.x * x1;
    acc0[1] += ea.y * x0; acc1[1] += ea.y * x1;
    acc0[2] += ea.z * x0; acc1[2] += ea.z * x1;
    acc0[3] += ea.w * x0; acc1[3] += ea.w * x1;
    acc0[4] += eb.x * x0; acc1[4] += eb.x * x1;
    acc0[5] += eb.y * x0; acc1[5] += eb.y * x1;
    acc0[6] += eb.z * x0; acc1[6] += eb.z * x1;
    acc0[7] += eb.w * x0; acc1[7] += eb.w * x1;
  }
  #pragma unroll
  for (int h = 0; h < H; ++h) {
    float2 o = {acc0[h], acc1[h]};
    *(float2*)&T8[(((size_t)chunk * B + b) * H + h) * D + e0] = o;
  }
}

// ------- attn[b,c] = (sumT8·Wv)/denom + bv; grid (B,H) -------
__global__ __launch_bounds__(256) void k_attn(const float* __restrict__ T8,
                                              const float* __restrict__ denom,
                                              const float* __restrict__ Wv,
                                              const float* __restrict__ bv,
                                              float* __restrict__ attn) {
  __shared__ float Ts[D];
  int b = blockIdx.x, h = blockIdx.y, t = threadIdx.x;
  for (int i = t; i < D; i += 256) {
    float s = 0.f;
    #pragma unroll
    for (int c2 = 0; c2 < 8; ++c2)
      s += T8[(((size_t)c2 * B + b) * H + h) * D + i];
    Ts[i] = s;
  }
  __syncthreads();
  int col = h * DH + (t >> 2), eq = t & 3;
  float acc = 0.f;
  const float* wp = Wv + (size_t)(eq * 128) * D + col;
  #pragma unroll 8
  for (int e = 0; e < 128; ++e) acc += Ts[eq * 128 + e] * wp[(size_t)e * D];
  acc += __shfl_xor(acc, 1); acc += __shfl_xor(acc, 2);
  if (eq == 0) attn[(size_t)b * D + col] = acc / denom[b * H + h] + bv[col];
}

// ------- x[b,c] = attn[b,:]·Wo[:,c] + bo[c] + ps[b,c]; grid (B,8) -------
__global__ __launch_bounds__(256) void k_x(const float* __restrict__ attn,
                                           const float* __restrict__ Wo,
                                           const float* __restrict__ bo,
                                           const float* __restrict__ ps,
                                           float* __restrict__ x) {
  __shared__ float As[D];
  int b = blockIdx.x, cg = blockIdx.y, t = threadIdx.x;
  for (int i = t; i < D; i += 256) As[i] = attn[(size_t)b * D + i];
  __syncthreads();
  int col = cg * 64 + (t >> 2), eq = t & 3;
  float acc = 0.f;
  const float* wp = Wo + (size_t)(eq * 128) * D + col;
  #pragma unroll 8
  for (int e = 0; e < 128; ++e) acc += As[eq * 128 + e] * wp[(size_t)e * D];
  acc += __shfl_xor(acc, 1); acc += __shfl_xor(acc, 2);
  if (eq == 0) x[(size_t)b * D + col] = acc + bo[col] + ps[(size_t)b * D + col];
}

// ------- fs = LN(x) per row; grid B, 512 thr -------
__global__ __launch_bounds__(512) void k_ln(const float* __restrict__ x,
                                            float* __restrict__ fs) {
  __shared__ float redS[8], redQ[8];
  __shared__ float sM, sI;
  int b = blockIdx.x, t = threadIdx.x;
  float v = x[(size_t)b * D + t];
  float s = v, sq = v * v;
  #pragma unroll
  for (int off = 32; off; off >>= 1) { s += __shfl_xor(s, off); sq += __shfl_xor(sq, off); }
  int wv = t >> 6, ln = t & 63;
  if (ln == 0) { redS[wv] = s; redQ[wv] = sq; }
  __syncthreads();
  if (t == 0) {
    float S = 0.f, Q = 0.f;
    #pragma unroll
    for (int i = 0; i < 8; ++i) { S += redS[i]; Q += redQ[i]; }
    float mean = S * (1.f / D);
    float var = Q * (1.f / D) - mean * mean;
    sM = mean; sI = rsqrtf(var + EPS);
  }
  __syncthreads();
  fs[(size_t)b * D + t] = (v - sM) * sI;
}

// ------- out = LN(hf_bf16 + gate*(alpha*fs[fb])); 1 wave/row, grid NF/4 -------
__global__ __launch_bounds__(256) void k_final(const ushort* __restrict__ hfb,
                                               const ushort* __restrict__ gateb,
                                               const float* __restrict__ alpha,
                                               const float* __restrict__ fs,
                                               const int* __restrict__ fb,
                                               float* __restrict__ out) {
  const int w = threadIdx.x >> 6, lane = threadIdx.x & 63;
  const int row = blockIdx.x * 4 + w;
  const int b = fb[row];
  const ushort* hr = hfb + (size_t)row * D + lane * 8;
  const ushort* gr = gateb + (size_t)row * D + lane * 8;
  const float* fr = fs + (size_t)b * D + lane * 8;
  const float* ar = alpha + lane * 8;
  union { ushort8v v; ushort u[8]; } uh, ug;
  uh.v = *(const ushort8v*)hr;
  ug.v = *(const ushort8v*)gr;
  float4 p0 = *(const float4*)fr, p1 = *(const float4*)(fr + 4);
  float4 a0 = *(const float4*)ar, a1 = *(const float4*)(ar + 4);
  float pv[8] = {p0.x, p0.y, p0.z, p0.w, p1.x, p1.y, p1.z, p1.w};
  float av[8] = {a0.x, a0.y, a0.z, a0.w, a1.x, a1.y, a1.z, a1.w};
  float x[8], s = 0.f, sq = 0.f;
  #pragma unroll
  for (int i = 0; i < 8; ++i) {
    x[i] = bf2f(uh.u[i]) + bf2f(ug.u[i]) * (av[i] * pv[i]);
    s += x[i]; sq += x[i] * x[i];
  }
  #pragma unroll
  for (int off = 32; off; off >>= 1) { s += __shfl_xor(s, off); sq += __shfl_xor(sq, off); }
  float mean = s * (1.f / D);
  float inv = rsqrtf(sq * (1.f / D) - mean * mean + EPS);
  float* op = out + (size_t)row * D + lane * 8;
  float4 o0 = {(x[0] - mean) * inv, (x[1] - mean) * inv, (x[2] - mean) * inv, (x[3] - mean) * inv};
  float4 o1 = {(x[4] - mean) * inv, (x[5] - mean) * inv, (x[6] - mean) * inv, (x[7] - mean) * inv};
  *(float4*)op = o0;
  *(float4*)(op + 4) = o1;
}

extern "C" void kernel_launch(void* const* d_in, const int* in_sizes, int n_in,
                              void* d_out, int out_size, void* d_ws, size_t ws_size,
                              hipStream_t stream) {
  const float* hf    = (const float*)d_in[0];
  const float* ho    = (const float*)d_in[1];
  const float* ps    = (const float*)d_in[2];
  const int*   fb    = (const int*)d_in[3];
  const int*   ob    = (const int*)d_in[4];
  const float* Wq    = (const float*)d_in[5];
  const float* bq    = (const float*)d_in[6];
  const float* Wk    = (const float*)d_in[7];
  const float* bk    = (const float*)d_in[8];
  const float* Wv    = (const float*)d_in[9];
  const float* bv    = (const float*)d_in[10];
  const float* Wo    = (const float*)d_in[11];
  const float* bo    = (const float*)d_in[12];
  const float* Wg    = (const float*)d_in[13];
  const float* bg    = (const float*)d_in[14];
  const float* alpha = (const float*)d_in[15];

  float* out    = (float*)d_out;
  float* fs_out = out + (size_t)NF * D;

  ushort* Wgt    = (ushort*)d_ws;                    // 512KB bf16 Wg^T
  ushort* gateb  = Wgt + 512 * 512;                  // 16MB bf16 gate
  ushort* nodesb = gateb + (size_t)NF * D;           // 24MB bf16 nodes (hf|ho)
  float* fbase   = (float*)(nodesb + (size_t)NT * D);
  float* Pk     = fbase;                   // B*H*D (1MB)
  float* qbk    = Pk + B * H * D;          // B*H
  float* scores = qbk + B * H;             // NT*H
  float* evals  = scores + (size_t)NT * H; // NT*H
  float* denom  = evals + (size_t)NT * H;  // B*H
  float* T8     = denom + B * H;           // 8*B*H*D (8MB)
  float* attn   = T8 + (size_t)8 * B * H * D; // B*D
  float* xbuf   = attn + B * D;            // B*D
  int* fstart   = (int*)(xbuf + B * D);    // B+1
  int* ostart   = fstart + (B + 1);        // B+1

  k_prep<<<PREP_TOTAL, 256, 0, stream>>>(ps, Wq, bq, Wk, bk, Wg, hf, ho, fb, ob,
                                         Pk, qbk, Wgt, nodesb, fstart, ostart);
  k_gate<<<dim3(NF / 128, 4), 256, 0, stream>>>(nodesb, Wgt, bg, gateb);
  k_scores<<<NT / 4, 256, 0, stream>>>(nodesb, fb, ob, Pk, qbk, scores);
  k_segsoftmax<<<B, 512, 0, stream>>>(scores, fstart, ostart, evals, denom);
  k_Taccum<<<dim3(B, 8), 256, 0, stream>>>(nodesb, fstart, ostart, evals, T8);
  k_attn<<<dim3(B, H), 256, 0, stream>>>(T8, denom, Wv, bv, attn);
  k_x<<<dim3(B, 8), 256, 0, stream>>>(attn, Wo, bo, ps, xbuf);
  k_ln<<<B, 512, 0, stream>>>(xbuf, fs_out);
  k_final<<<NF / 4, 256, 0, stream>>>(nodesb, gateb, alpha, fs_out, fb, out);
}

// Round 13
// 130.238 us; speedup vs baseline: 1.0311x; 1.0311x over previous
//
#include <hip/hip_runtime.h>
#include <hip/hip_bf16.h>
#include <math.h>

constexpr int D  = 512;
constexpr int H  = 8;
constexpr int DH = 64;
constexpr int B  = 64;
constexpr int NF = 16384;
constexpr int NO = 8192;
constexpr int NT = NF + NO;
constexpr float EPS = 1e-5f;
constexpr float LOG2E = 1.4426950408889634f;

constexpr int PREP_PK   = 512;                  // (b,h) blocks
constexpr int PREP_BND  = PREP_PK;              // 1 block
constexpr int PREP_WG0  = PREP_BND + 1;         // 256 blocks
constexpr int PREP_CVT0 = PREP_WG0 + 256;       // 6144 blocks
constexpr int CVT_BLOCKS = NT * D / 2048;       // 6144
constexpr int PREP_TOTAL = PREP_CVT0 + CVT_BLOCKS;

typedef short short8 __attribute__((ext_vector_type(8)));
typedef float f32x4 __attribute__((ext_vector_type(4)));
typedef unsigned short ushort;
typedef ushort ushort8v __attribute__((ext_vector_type(8)));

__device__ __forceinline__ ushort f2bf(float f) {
  unsigned int x = __float_as_uint(f);
  x += 0x7FFF + ((x >> 16) & 1);   // RNE (inputs finite)
  return (ushort)(x >> 16);
}
__device__ __forceinline__ float bf2f(ushort u) {
  return __uint_as_float(((unsigned int)u) << 16);
}
__device__ __forceinline__ float fast_exp(float x) {   // e^x
  return __builtin_amdgcn_exp2f(x * LOG2E);
}
__device__ __forceinline__ float fast_sigmoid(float z) {
  return __builtin_amdgcn_rcpf(1.0f + __builtin_amdgcn_exp2f(-z * LOG2E));
}
// 8 fp32 -> 8 bf16 (RNE); compiler emits v_cvt_pk_bf16_f32 pairs
__device__ __forceinline__ short8 cvt8(float4 f0, float4 f1) {
  union { short8 v; __hip_bfloat162 h[4]; } u;
  u.h[0] = __float22bfloat162_rn(float2{f0.x, f0.y});
  u.h[1] = __float22bfloat162_rn(float2{f0.z, f0.w});
  u.h[2] = __float22bfloat162_rn(float2{f1.x, f1.y});
  u.h[3] = __float22bfloat162_rn(float2{f1.z, f1.w});
  return u.v;
}
// async global->LDS, 16B per lane; lds dest = wave-uniform base + lane*16
__device__ __forceinline__ void gll16(const void* g, void* l) {
  __builtin_amdgcn_global_load_lds(
      (const __attribute__((address_space(1))) void*)g,
      (__attribute__((address_space(3))) void*)l, 16, 0, 0);
}

// ======== k_prep: [0..511] q-slice+Pk+qbk per (b,h); [512] bounds; ========
// ======== [513..768] Wg^T bf16; [769..6912] node fp32->bf16 cvt     ========
__global__ __launch_bounds__(256) void k_prep(const float* __restrict__ ps,
                                              const float* __restrict__ Wq,
                                              const float* __restrict__ bq,
                                              const float* __restrict__ Wk,
                                              const float* __restrict__ bk,
                                              const float* __restrict__ Wg,
                                              const float* __restrict__ hf,
                                              const float* __restrict__ ho,
                                              const int* __restrict__ fb,
                                              const int* __restrict__ ob,
                                              float* __restrict__ Pk,
                                              float* __restrict__ qbk,
                                              ushort* __restrict__ Wgt,
                                              ushort* __restrict__ nodesb,
                                              int* __restrict__ fstart,
                                              int* __restrict__ ostart) {
  __shared__ float shm[1056];   // pk: [0..511]=ps row, [512..575]=q slice; prepW: 32x33 tile
  const int bid = blockIdx.x, t = threadIdx.x;
  if (bid < PREP_PK) {
    const int b = bid >> 3, h = bid & 7;
    for (int i = t; i < D; i += 256) shm[i] = ps[(size_t)b * D + i];
    __syncthreads();
    // q[col] for col in [h*64, h*64+64): 4 threads per col
    {
      const int j = t >> 2, eq = t & 3;
      const int col = h * 64 + j;
      float acc = 0.f;
      const float* wp = Wq + (size_t)(eq * 128) * D + col;
      #pragma unroll 8
      for (int e = 0; e < 128; ++e) acc += shm[eq * 128 + e] * wp[(size_t)e * D];
      acc += __shfl_xor(acc, 1); acc += __shfl_xor(acc, 2);
      if (eq == 0) shm[512 + j] = acc + bq[col];
    }
    __syncthreads();
    for (int e = t; e < D; e += 256) {
      float acc = 0.f;
      #pragma unroll 8
      for (int j = 0; j < DH; ++j) acc += Wk[(size_t)e * D + h * DH + j] * shm[512 + j];
      Pk[((size_t)b * H + h) * D + e] = acc;
    }
    if (t == 0) {
      float s = 0.f;
      for (int j = 0; j < DH; ++j) s += bk[h * DH + j] * shm[512 + j];
      qbk[b * H + h] = s;
    }
  } else if (bid == PREP_BND) {
    if (t <= B) {
      int lo = 0, hi = NF;
      while (lo < hi) { int mid = (lo + hi) >> 1; if (fb[mid] < t) lo = mid + 1; else hi = mid; }
      fstart[t] = lo;
    } else if (t >= 128 && t <= 128 + B) {
      int v = t - 128;
      int lo = 0, hi = NO;
      while (lo < hi) { int mid = (lo + hi) >> 1; if (ob[mid] < v) lo = mid + 1; else hi = mid; }
      ostart[v] = lo;
    }
  } else if (bid < PREP_CVT0) {
    // Wg transpose 32x32 tiles, 16x16 grid
    float (*tile)[33] = (float(*)[33])shm;
    const int tb = bid - PREP_WG0;
    const int bx = tb & 15, by = tb >> 4;
    const int tx = t & 31, ty = t >> 5;            // ty 0..7
    #pragma unroll
    for (int i = 0; i < 4; ++i)
      tile[ty + i * 8][tx] = Wg[(size_t)(by * 32 + ty + i * 8) * D + bx * 32 + tx];
    __syncthreads();
    #pragma unroll
    for (int i = 0; i < 4; ++i)
      Wgt[(size_t)(bx * 32 + ty + i * 8) * D + by * 32 + tx] = f2bf(tile[tx][ty + i * 8]);
  } else {
    // nodes fp32 -> bf16: 2048 elems per block
    size_t idx = (size_t)(bid - PREP_CVT0) * 2048 + (size_t)t * 8;
    const float* src = (idx < (size_t)NF * D) ? (hf + idx) : (ho + (idx - (size_t)NF * D));
    float4 f0 = *(const float4*)src, f1 = *(const float4*)(src + 4);
    *(short8*)(nodesb + idx) = cvt8(f0, f1);
  }
}

// ------- gate GEMM: gateb = bf16(sigmoid(hf @ Wg + bg)); 128x128, BK=32, all-bf16 LDS ----
__global__ __launch_bounds__(256) void k_gate(const ushort* __restrict__ hfb,
                                              const ushort* __restrict__ Wgt,
                                              const float* __restrict__ bg,
                                              ushort* __restrict__ gateb) {
  __shared__ ushort Asb[2][4096];   // 8KB/buf: [128 rows][32 k] bf16, chunk-swizzled
  __shared__ ushort Bs[2][4096];    // 8KB/buf: [128 cols][32 k] bf16, chunk-swizzled
  const int tid = threadIdx.x, lane = tid & 63, w = tid >> 6;
  const int rowBase = blockIdx.x * 128, colBase = blockIdx.y * 128;
  const int wm = w >> 1, wn = w & 1;
  const int lrow = lane & 15, kg = lane >> 4;

  int ra[2], ca[2], cb[2], cc[2];
  #pragma unroll
  for (int j = 0; j < 2; ++j) {
    int ia = (w * 2 + j) * 64 + lane;          // 0..511
    ra[j] = ia >> 2;                           // row/col 0..127
    ca[j] = (ia & 3) ^ ((ra[j] >> 1) & 3);     // 16B-chunk swizzle
    cb[j] = ra[j];
    cc[j] = ca[j];
  }

#define STAGE(buf, k0)                                                          \
  {                                                                             \
    _Pragma("unroll")                                                           \
    for (int j = 0; j < 2; ++j)                                                 \
      gll16(hfb + (size_t)(rowBase + ra[j]) * D + (k0) + ca[j] * 8,             \
            &Asb[buf][(w * 2 + j) * 512]);                                      \
    _Pragma("unroll")                                                           \
    for (int j = 0; j < 2; ++j)                                                 \
      gll16(Wgt + (size_t)(colBase + cb[j]) * D + (k0) + cc[j] * 8,             \
            &Bs[buf][(w * 2 + j) * 512]);                                       \
  }

  STAGE(0, 0);
  __syncthreads();

  f32x4 acc[4][4] = {};
  for (int t = 0; t < 16; ++t) {
    const int cur = t & 1;
    if (t < 15) STAGE(cur ^ 1, (t + 1) * 32);
    short8 av[4], bv[4];
    #pragma unroll
    for (int m = 0; m < 4; ++m) {
      const int a_r = wm * 64 + m * 16 + lrow;
      av[m] = *(const short8*)&Asb[cur][a_r * 32 + (kg ^ ((a_r >> 1) & 3)) * 8];
    }
    #pragma unroll
    for (int n = 0; n < 4; ++n) {
      const int b_c = wn * 64 + n * 16 + lrow;
      bv[n] = *(const short8*)&Bs[cur][b_c * 32 + (kg ^ ((b_c >> 1) & 3)) * 8];
    }
    #pragma unroll
    for (int m = 0; m < 4; ++m)
      #pragma unroll
      for (int n = 0; n < 4; ++n)
        acc[m][n] = __builtin_amdgcn_mfma_f32_16x16x32_bf16(av[m], bv[n], acc[m][n], 0, 0, 0);
    __syncthreads();
  }
#undef STAGE

  // epilogue: sigmoid + bias -> bf16 global.  C/D map: col=lane&15, row=(lane>>4)*4+reg
  #pragma unroll
  for (int n = 0; n < 4; ++n) {
    const int col = colBase + wn * 64 + n * 16 + lrow;
    const float bgv = bg[col];
    #pragma unroll
    for (int m = 0; m < 4; ++m) {
      const int row0 = rowBase + wm * 64 + m * 16 + kg * 4;
      #pragma unroll
      for (int r = 0; r < 4; ++r)
        gateb[(size_t)(row0 + r) * D + col] = f2bf(fast_sigmoid(acc[m][n][r] + bgv));
    }
  }
}

// ------- scores[n,h] = (nodes[n]·Pk[seg,h] + qbk[seg,h]) / 8 ;  wave per node -------
__global__ __launch_bounds__(256) void k_scores(const ushort* __restrict__ nodesb,
                                                const int* __restrict__ fb,
                                                const int* __restrict__ ob,
                                                const float* __restrict__ Pk,
                                                const float* __restrict__ qbk,
                                                float* __restrict__ scores) {
  int lane = threadIdx.x & 63;
  int n = blockIdx.x * 4 + (threadIdx.x >> 6);
  int b = (n < NF) ? fb[n] : ob[n - NF];
  union { short8 v; ushort u[8]; } ux;
  ux.v = *(const short8*)(nodesb + (size_t)n * D + lane * 8);
  float xf[8];
  #pragma unroll
  for (int i = 0; i < 8; ++i) xf[i] = bf2f(ux.u[i]);
  float acc[H];
  #pragma unroll
  for (int h = 0; h < H; ++h) {
    const float4* p4 = (const float4*)(Pk + ((size_t)b * H + h) * D) + lane * 2;
    float4 p0 = p4[0], p1 = p4[1];
    acc[h] = xf[0] * p0.x + xf[1] * p0.y + xf[2] * p0.z + xf[3] * p0.w +
             xf[4] * p1.x + xf[5] * p1.y + xf[6] * p1.z + xf[7] * p1.w;
  }
  #pragma unroll
  for (int h = 0; h < H; ++h) {
    float v = acc[h];
    #pragma unroll
    for (int off = 32; off; off >>= 1) v += __shfl_xor(v, off);
    if (lane == h) scores[(size_t)n * H + h] = (v + qbk[b * H + h]) * 0.125f;
  }
}

// ------- per (b,h): segment max, e = exp(s-m), denom -------
__global__ __launch_bounds__(512) void k_segsoftmax(const float* __restrict__ scores,
                                                    const int* __restrict__ fstart,
                                                    const int* __restrict__ ostart,
                                                    float* __restrict__ evals,
                                                    float* __restrict__ denom) {
  int b = blockIdx.x;
  int h = threadIdx.x >> 6, lane = threadIdx.x & 63;
  int f0 = fstart[b], f1 = fstart[b + 1];
  int o0 = ostart[b], o1 = ostart[b + 1];
  float m = -1e30f;
  for (int i = f0 + lane; i < f1; i += 64) m = fmaxf(m, scores[(size_t)i * H + h]);
  for (int i = o0 + lane; i < o1; i += 64) m = fmaxf(m, scores[(size_t)(NF + i) * H + h]);
  #pragma unroll
  for (int off = 32; off; off >>= 1) m = fmaxf(m, __shfl_xor(m, off));
  float s = 0.f;
  for (int i = f0 + lane; i < f1; i += 64) {
    float e = fast_exp(scores[(size_t)i * H + h] - m);
    evals[(size_t)i * H + h] = e; s += e;
  }
  for (int i = o0 + lane; i < o1; i += 64) {
    float e = fast_exp(scores[(size_t)(NF + i) * H + h] - m);
    evals[(size_t)(NF + i) * H + h] = e; s += e;
  }
  #pragma unroll
  for (int off = 32; off; off >>= 1) s += __shfl_xor(s, off);
  if (lane == 0) denom[b * H + h] = s;
}

// ------- T8[chunk][b][h][e] = sum_{n in chunk of seg b} e[n,h]*nodes[n,e]; no atomics ----
__global__ __launch_bounds__(512) void k_Taccum(const ushort* __restrict__ nodesb,
                                                const int* __restrict__ fstart,
                                                const int* __restrict__ ostart,
                                                const float* __restrict__ evals,
                                                float* __restrict__ T8) {
  int b = blockIdx.x, chunk = blockIdx.y;
  int e = threadIdx.x;
  int f0 = fstart[b], flen = fstart[b + 1] - f0;
  int o0 = ostart[b], olen = ostart[b + 1] - o0;
  int L = flen + olen;
  float acc[8] = {0.f, 0.f, 0.f, 0.f, 0.f, 0.f, 0.f, 0.f};
  for (int idx = chunk; idx < L; idx += 8) {
    int n = (idx < flen) ? (f0 + idx) : (NF + o0 + (idx - flen));
    float x = bf2f(nodesb[(size_t)n * D + e]);
    const float4* ev = (const float4*)(evals + (size_t)n * H);
    float4 e0 = ev[0], e1 = ev[1];
    acc[0] += e0.x * x; acc[1] += e0.y * x; acc[2] += e0.z * x; acc[3] += e0.w * x;
    acc[4] += e1.x * x; acc[5] += e1.y * x; acc[6] += e1.z * x; acc[7] += e1.w * x;
  }
  #pragma unroll
  for (int h = 0; h < H; ++h)
    T8[(((size_t)chunk * B + b) * H + h) * D + e] = acc[h];
}

// ------- attn[b,c] = (sumT8·Wv)/denom + bv; grid (B,H) -------
__global__ __launch_bounds__(256) void k_attn(const float* __restrict__ T8,
                                              const float* __restrict__ denom,
                                              const float* __restrict__ Wv,
                                              const float* __restrict__ bv,
                                              float* __restrict__ attn) {
  __shared__ float Ts[D];
  int b = blockIdx.x, h = blockIdx.y, t = threadIdx.x;
  for (int i = t; i < D; i += 256) {
    float s = 0.f;
    #pragma unroll
    for (int c2 = 0; c2 < 8; ++c2)
      s += T8[(((size_t)c2 * B + b) * H + h) * D + i];
    Ts[i] = s;
  }
  __syncthreads();
  int col = h * DH + (t >> 2), eq = t & 3;
  float acc = 0.f;
  const float* wp = Wv + (size_t)(eq * 128) * D + col;
  #pragma unroll 8
  for (int e = 0; e < 128; ++e) acc += Ts[eq * 128 + e] * wp[(size_t)e * D];
  acc += __shfl_xor(acc, 1); acc += __shfl_xor(acc, 2);
  if (eq == 0) attn[(size_t)b * D + col] = acc / denom[b * H + h] + bv[col];
}

// ------- x[b,c] = attn[b,:]·Wo[:,c] + bo[c] + ps[b,c]; grid (B,8) -------
__global__ __launch_bounds__(256) void k_x(const float* __restrict__ attn,
                                           const float* __restrict__ Wo,
                                           const float* __restrict__ bo,
                                           const float* __restrict__ ps,
                                           float* __restrict__ x) {
  __shared__ float As[D];
  int b = blockIdx.x, cg = blockIdx.y, t = threadIdx.x;
  for (int i = t; i < D; i += 256) As[i] = attn[(size_t)b * D + i];
  __syncthreads();
  int col = cg * 64 + (t >> 2), eq = t & 3;
  float acc = 0.f;
  const float* wp = Wo + (size_t)(eq * 128) * D + col;
  #pragma unroll 8
  for (int e = 0; e < 128; ++e) acc += As[eq * 128 + e] * wp[(size_t)e * D];
  acc += __shfl_xor(acc, 1); acc += __shfl_xor(acc, 2);
  if (eq == 0) x[(size_t)b * D + col] = acc + bo[col] + ps[(size_t)b * D + col];
}

// ------- fs = LN(x) per row; grid B, 512 thr -------
__global__ __launch_bounds__(512) void k_ln(const float* __restrict__ x,
                                            float* __restrict__ fs) {
  __shared__ float redS[8], redQ[8];
  __shared__ float sM, sI;
  int b = blockIdx.x, t = threadIdx.x;
  float v = x[(size_t)b * D + t];
  float s = v, sq = v * v;
  #pragma unroll
  for (int off = 32; off; off >>= 1) { s += __shfl_xor(s, off); sq += __shfl_xor(sq, off); }
  int wv = t >> 6, ln = t & 63;
  if (ln == 0) { redS[wv] = s; redQ[wv] = sq; }
  __syncthreads();
  if (t == 0) {
    float S = 0.f, Q = 0.f;
    #pragma unroll
    for (int i = 0; i < 8; ++i) { S += redS[i]; Q += redQ[i]; }
    float mean = S * (1.f / D);
    float var = Q * (1.f / D) - mean * mean;
    sM = mean; sI = rsqrtf(var + EPS);
  }
  __syncthreads();
  fs[(size_t)b * D + t] = (v - sM) * sI;
}

// ------- out = LN(hf_bf16 + gate*(alpha*fs[fb])); 1 wave/row, grid NF/4 -------
__global__ __launch_bounds__(256) void k_final(const ushort* __restrict__ hfb,
                                               const ushort* __restrict__ gateb,
                                               const float* __restrict__ alpha,
                                               const float* __restrict__ fs,
                                               const int* __restrict__ fb,
                                               float* __restrict__ out) {
  const int w = threadIdx.x >> 6, lane = threadIdx.x & 63;
  const int row = blockIdx.x * 4 + w;
  const int b = fb[row];
  const ushort* hr = hfb + (size_t)row * D + lane * 8;
  const ushort* gr = gateb + (size_t)row * D + lane * 8;
  const float* fr = fs + (size_t)b * D + lane * 8;
  const float* ar = alpha + lane * 8;
  union { ushort8v v; ushort u[8]; } uh, ug;
  uh.v = *(const ushort8v*)hr;
  ug.v = *(const ushort8v*)gr;
  float4 p0 = *(const float4*)fr, p1 = *(const float4*)(fr + 4);
  float4 a0 = *(const float4*)ar, a1 = *(const float4*)(ar + 4);
  float pv[8] = {p0.x, p0.y, p0.z, p0.w, p1.x, p1.y, p1.z, p1.w};
  float av[8] = {a0.x, a0.y, a0.z, a0.w, a1.x, a1.y, a1.z, a1.w};
  float x[8], s = 0.f, sq = 0.f;
  #pragma unroll
  for (int i = 0; i < 8; ++i) {
    x[i] = bf2f(uh.u[i]) + bf2f(ug.u[i]) * (av[i] * pv[i]);
    s += x[i]; sq += x[i] * x[i];
  }
  #pragma unroll
  for (int off = 32; off; off >>= 1) { s += __shfl_xor(s, off); sq += __shfl_xor(sq, off); }
  float mean = s * (1.f / D);
  float inv = rsqrtf(sq * (1.f / D) - mean * mean + EPS);
  float* op = out + (size_t)row * D + lane * 8;
  float4 o0 = {(x[0] - mean) * inv, (x[1] - mean) * inv, (x[2] - mean) * inv, (x[3] - mean) * inv};
  float4 o1 = {(x[4] - mean) * inv, (x[5] - mean) * inv, (x[6] - mean) * inv, (x[7] - mean) * inv};
  *(float4*)op = o0;
  *(float4*)(op + 4) = o1;
}

extern "C" void kernel_launch(void* const* d_in, const int* in_sizes, int n_in,
                              void* d_out, int out_size, void* d_ws, size_t ws_size,
                              hipStream_t stream) {
  const float* hf    = (const float*)d_in[0];
  const float* ho    = (const float*)d_in[1];
  const float* ps    = (const float*)d_in[2];
  const int*   fb    = (const int*)d_in[3];
  const int*   ob    = (const int*)d_in[4];
  const float* Wq    = (const float*)d_in[5];
  const float* bq    = (const float*)d_in[6];
  const float* Wk    = (const float*)d_in[7];
  const float* bk    = (const float*)d_in[8];
  const float* Wv    = (const float*)d_in[9];
  const float* bv    = (const float*)d_in[10];
  const float* Wo    = (const float*)d_in[11];
  const float* bo    = (const float*)d_in[12];
  const float* Wg    = (const float*)d_in[13];
  const float* bg    = (const float*)d_in[14];
  const float* alpha = (const float*)d_in[15];

  float* out    = (float*)d_out;
  float* fs_out = out + (size_t)NF * D;

  ushort* Wgt    = (ushort*)d_ws;                    // 512KB bf16 Wg^T
  ushort* gateb  = Wgt + 512 * 512;                  // 16MB bf16 gate
  ushort* nodesb = gateb + (size_t)NF * D;           // 24MB bf16 nodes (hf|ho)
  float* fbase   = (float*)(nodesb + (size_t)NT * D);
  float* Pk     = fbase;                   // B*H*D (1MB)
  float* qbk    = Pk + B * H * D;          // B*H
  float* scores = qbk + B * H;             // NT*H
  float* evals  = scores + (size_t)NT * H; // NT*H
  float* denom  = evals + (size_t)NT * H;  // B*H
  float* T8     = denom + B * H;           // 8*B*H*D (8MB)
  float* attn   = T8 + (size_t)8 * B * H * D; // B*D
  float* xbuf   = attn + B * D;            // B*D
  int* fstart   = (int*)(xbuf + B * D);    // B+1
  int* ostart   = fstart + (B + 1);        // B+1

  k_prep<<<PREP_TOTAL, 256, 0, stream>>>(ps, Wq, bq, Wk, bk, Wg, hf, ho, fb, ob,
                                         Pk, qbk, Wgt, nodesb, fstart, ostart);
  k_gate<<<dim3(NF / 128, 4), 256, 0, stream>>>(nodesb, Wgt, bg, gateb);
  k_scores<<<NT / 4, 256, 0, stream>>>(nodesb, fb, ob, Pk, qbk, scores);
  k_segsoftmax<<<B, 512, 0, stream>>>(scores, fstart, ostart, evals, denom);
  k_Taccum<<<dim3(B, 8), 512, 0, stream>>>(nodesb, fstart, ostart, evals, T8);
  k_attn<<<dim3(B, H), 256, 0, stream>>>(T8, denom, Wv, bv, attn);
  k_x<<<dim3(B, 8), 256, 0, stream>>>(attn, Wo, bo, ps, xbuf);
  k_ln<<<B, 512, 0, stream>>>(xbuf, fs_out);
  k_final<<<NF / 4, 256, 0, stream>>>(nodesb, gateb, alpha, fs_out, fb, out);
}